// Round 1
// baseline (4227.977 us; speedup 1.0000x reference)
//
#include <hip/hip_runtime.h>
#include <hip/hip_bf16.h>
#include <math.h>

#define H 512
#define NT 6          // edge types
#define BM 64
#define BN 64
#define BK 16

__device__ __forceinline__ float sigmoidf_(float x) { return 1.0f / (1.0f + expf(-x)); }

// ---------------- edge-type counting sort ----------------
// meta layout (ints): [0..7]=counts, [8..14]=paddedStart (NT+1 used), [16..23]=cursor
__global__ void hist_kernel(const int* __restrict__ etype, int E, int* __restrict__ meta) {
    int i = blockIdx.x * blockDim.x + threadIdx.x;
    if (i < E) atomicAdd(&meta[etype[i]], 1);
}

__global__ void prefix_kernel(int* __restrict__ meta) {
    if (threadIdx.x == 0 && blockIdx.x == 0) {
        int acc = 0;
        for (int t = 0; t < NT; ++t) {
            meta[8 + t]  = acc;   // padded bucket start
            meta[16 + t] = acc;   // scatter cursor
            acc += ((meta[t] + BM - 1) / BM) * BM;
        }
        meta[8 + NT] = acc;       // padded total
    }
}

__global__ void scatter_perm_kernel(const int* __restrict__ etype, int E,
                                    int* __restrict__ meta, int* __restrict__ perm) {
    int i = blockIdx.x * blockDim.x + threadIdx.x;
    if (i < E) {
        int pos = atomicAdd(&meta[16 + etype[i]], 1);
        perm[pos] = i;
    }
}

// ---------------- per-type edge message GEMM + scatter-add ----------------
// C[e, :] = emb[src[e], :] @ W_edge[:, t*H : t*H+H] + b_edge[t*H:...]
// scattered: proposed[dst[e], :] += C[e, :]
__global__ __launch_bounds__(256)
void edge_msg_kernel(const float* __restrict__ emb,
                     const int* __restrict__ src_idx,
                     const int* __restrict__ dst_idx,
                     const float* __restrict__ W_edge,
                     const float* __restrict__ b_edge,
                     const int* __restrict__ meta,
                     const int* __restrict__ perm,
                     float* __restrict__ proposed)
{
    __shared__ float As[BK][BM];   // transposed A tile
    __shared__ float Bs[BK][BN];
    __shared__ int   ls_e[BM];
    __shared__ int   ls_srcbase[BM];

    const int rowBase = blockIdx.y * BM;
    const int paddedTotal = meta[8 + NT];
    if (rowBase >= paddedTotal) return;
    int t = 0;
    while (rowBase >= meta[8 + t + 1]) ++t;   // bucket of this tile (tiles never straddle buckets)

    const int colBase = blockIdx.x * BN;
    const int tid = threadIdx.x;

    if (tid < BM) {
        int e = perm[rowBase + tid];
        ls_e[tid] = e;
        ls_srcbase[tid] = (e >= 0) ? src_idx[e] * H : -1;
    }
    __syncthreads();

    const int tx = tid & 15;        // col group
    const int ty = tid >> 4;        // row group
    const int mA = tid >> 2;        // A staging: row 0..63
    const int kA = (tid & 3) * 4;   // A staging: k 0,4,8,12
    const int kB = tid >> 4;        // B staging: k 0..15
    const int jB = (tid & 15) * 4;  // B staging: col

    float acc[4][4] = {};

    for (int k0 = 0; k0 < H; k0 += BK) {
        {
            int sb = ls_srcbase[mA];
            float4 v = make_float4(0.f, 0.f, 0.f, 0.f);
            if (sb >= 0) v = *(const float4*)&emb[sb + k0 + kA];
            As[kA + 0][mA] = v.x; As[kA + 1][mA] = v.y;
            As[kA + 2][mA] = v.z; As[kA + 3][mA] = v.w;
        }
        {
            float4 v = *(const float4*)&W_edge[(size_t)(k0 + kB) * (NT * H) + t * H + colBase + jB];
            *(float4*)&Bs[kB][jB] = v;
        }
        __syncthreads();
        #pragma unroll
        for (int k = 0; k < BK; ++k) {
            float4 av = *(const float4*)&As[k][ty * 4];
            float4 bv = *(const float4*)&Bs[k][tx * 4];
            float a[4] = {av.x, av.y, av.z, av.w};
            float b[4] = {bv.x, bv.y, bv.z, bv.w};
            #pragma unroll
            for (int i = 0; i < 4; ++i)
                #pragma unroll
                for (int j = 0; j < 4; ++j)
                    acc[i][j] = fmaf(a[i], b[j], acc[i][j]);
        }
        __syncthreads();
    }

    #pragma unroll
    for (int i = 0; i < 4; ++i) {
        int m = ty * 4 + i;
        int e = ls_e[m];
        if (e < 0) continue;
        int d = dst_idx[e];
        #pragma unroll
        for (int j = 0; j < 4; ++j) {
            int col = colBase + tx * 4 + j;
            atomicAdd(&proposed[(size_t)d * H + col], acc[i][j] + b_edge[t * H + col]);
        }
    }
}

// ---------------- fused GRU: 6 matmuls + activations ----------------
__global__ __launch_bounds__(256)
void gru_kernel(const float* __restrict__ emb,
                const float* __restrict__ proposed,
                const float* __restrict__ Wir, const float* __restrict__ Wiz,
                const float* __restrict__ Win,
                const float* __restrict__ bir, const float* __restrict__ biz,
                const float* __restrict__ bin,
                const float* __restrict__ Whr, const float* __restrict__ Whz,
                const float* __restrict__ Whn,
                const float* __restrict__ bhn,
                float* __restrict__ out, int N)
{
    __shared__ float A1s[BK][BM];       // proposed tile (transposed)
    __shared__ float A2s[BK][BM];       // h tile (transposed)
    __shared__ float Bs[6][BK][BN];

    const int rowBase = blockIdx.y * BM;
    const int colBase = blockIdx.x * BN;
    const int tid = threadIdx.x;
    const int tx = tid & 15, ty = tid >> 4;
    const int mA = tid >> 2;
    const int kA = (tid & 3) * 4;
    const int kB = tid >> 4;
    const int jB = (tid & 15) * 4;

    const int row_mA = rowBase + mA;
    const bool validA = row_mA < N;

    float acc[6][4][4] = {};

    for (int k0 = 0; k0 < H; k0 += BK) {
        float4 v1 = make_float4(0.f, 0.f, 0.f, 0.f), v2 = v1;
        if (validA) {
            v1 = *(const float4*)&proposed[(size_t)row_mA * H + k0 + kA];
            v2 = *(const float4*)&emb[(size_t)row_mA * H + k0 + kA];
        }
        A1s[kA + 0][mA] = v1.x; A1s[kA + 1][mA] = v1.y;
        A1s[kA + 2][mA] = v1.z; A1s[kA + 3][mA] = v1.w;
        A2s[kA + 0][mA] = v2.x; A2s[kA + 1][mA] = v2.y;
        A2s[kA + 2][mA] = v2.z; A2s[kA + 3][mA] = v2.w;

        const float* Wp[6] = {Wir, Wiz, Win, Whr, Whz, Whn};
        #pragma unroll
        for (int w = 0; w < 6; ++w)
            *(float4*)&Bs[w][kB][jB] = *(const float4*)&Wp[w][(size_t)(k0 + kB) * H + colBase + jB];
        __syncthreads();

        #pragma unroll
        for (int k = 0; k < BK; ++k) {
            float4 a1v = *(const float4*)&A1s[k][ty * 4];
            float4 a2v = *(const float4*)&A2s[k][ty * 4];
            float a1[4] = {a1v.x, a1v.y, a1v.z, a1v.w};
            float a2[4] = {a2v.x, a2v.y, a2v.z, a2v.w};
            #pragma unroll
            for (int w = 0; w < 6; ++w) {
                float4 bv = *(const float4*)&Bs[w][k][tx * 4];
                float b[4] = {bv.x, bv.y, bv.z, bv.w};
                #pragma unroll
                for (int i = 0; i < 4; ++i) {
                    float a = (w < 3) ? a1[i] : a2[i];
                    #pragma unroll
                    for (int j = 0; j < 4; ++j)
                        acc[w][i][j] = fmaf(a, b[j], acc[w][i][j]);
                }
            }
        }
        __syncthreads();
    }

    #pragma unroll
    for (int i = 0; i < 4; ++i) {
        int row = rowBase + ty * 4 + i;
        if (row >= N) continue;
        #pragma unroll
        for (int j = 0; j < 4; ++j) {
            int col = colBase + tx * 4 + j;
            float pr = acc[0][i][j] + bir[col];
            float pz = acc[1][i][j] + biz[col];
            float pn = acc[2][i][j] + bin[col];
            float hr = acc[3][i][j];
            float hz = acc[4][i][j];
            float hn = acc[5][i][j] + bhn[col];
            float rg = sigmoidf_(pr + hr);
            float zg = sigmoidf_(pz + hz);
            float ng = tanhf(pn + rg * hn);
            float h  = emb[(size_t)row * H + col];
            out[(size_t)row * H + col] = (1.0f - zg) * ng + zg * h;
        }
    }
}

extern "C" void kernel_launch(void* const* d_in, const int* in_sizes, int n_in,
                              void* d_out, int out_size, void* d_ws, size_t ws_size,
                              hipStream_t stream) {
    const float* emb     = (const float*)d_in[0];
    const int*   src_idx = (const int*)d_in[1];
    const int*   dst_idx = (const int*)d_in[2];
    const int*   etype   = (const int*)d_in[3];
    const float* W_edge  = (const float*)d_in[6];
    const float* b_edge  = (const float*)d_in[7];
    const float* Wir = (const float*)d_in[8];
    const float* Wiz = (const float*)d_in[9];
    const float* Win = (const float*)d_in[10];
    const float* bir = (const float*)d_in[11];
    const float* biz = (const float*)d_in[12];
    const float* bin = (const float*)d_in[13];
    const float* Whr = (const float*)d_in[14];
    const float* Whz = (const float*)d_in[15];
    const float* Whn = (const float*)d_in[16];
    const float* bhn = (const float*)d_in[17];

    const int E = in_sizes[1];
    const int N = in_sizes[0] / H;

    float* proposed = (float*)d_ws;
    int*   meta     = (int*)((char*)d_ws + (size_t)N * H * sizeof(float));
    int*   perm     = meta + 32;
    const int maxRowTiles = (E + BM - 1) / BM + NT;

    hipMemsetAsync(proposed, 0, (size_t)N * H * sizeof(float), stream);
    hipMemsetAsync(meta, 0, 32 * sizeof(int), stream);
    hipMemsetAsync(perm, 0xFF, (size_t)maxRowTiles * BM * sizeof(int), stream);

    hist_kernel<<<(E + 255) / 256, 256, 0, stream>>>(etype, E, meta);
    prefix_kernel<<<1, 64, 0, stream>>>(meta);
    scatter_perm_kernel<<<(E + 255) / 256, 256, 0, stream>>>(etype, E, meta, perm);

    dim3 egrid(H / BN, maxRowTiles);
    edge_msg_kernel<<<egrid, 256, 0, stream>>>(emb, src_idx, dst_idx, W_edge, b_edge,
                                               meta, perm, proposed);

    dim3 ggrid(H / BN, (N + BM - 1) / BM);
    gru_kernel<<<ggrid, 256, 0, stream>>>(emb, proposed, Wir, Wiz, Win, bir, biz, bin,
                                          Whr, Whz, Whn, bhn, (float*)d_out, N);
}

// Round 2
// 1782.295 us; speedup vs baseline: 2.3722x; 2.3722x over previous
//
#include <hip/hip_runtime.h>
#include <hip/hip_bf16.h>
#include <math.h>

#define H 512
#define NT 6
#define BM 64
#define BN 64
#define BK 32
#define LDW (BK + 8)   // LDS row pitch in shorts (pad 16B)

typedef short bf16x8 __attribute__((ext_vector_type(8)));
typedef float f32x4 __attribute__((ext_vector_type(4)));

__device__ __forceinline__ float sigmoidf_(float x) { return 1.0f / (1.0f + expf(-x)); }

__device__ __forceinline__ unsigned short f2bf(float f) {
    unsigned int u = __float_as_uint(f);
    u = (u + 0x7FFF + ((u >> 16) & 1)) >> 16;
    return (unsigned short)u;
}

// ---------------- edge-type counting sort ----------------
__global__ void hist_kernel(const int* __restrict__ etype, int E, int* __restrict__ meta) {
    int i = blockIdx.x * blockDim.x + threadIdx.x;
    if (i < E) atomicAdd(&meta[etype[i]], 1);
}

__global__ void prefix_kernel(int* __restrict__ meta) {
    if (threadIdx.x == 0 && blockIdx.x == 0) {
        int acc = 0;
        for (int t = 0; t < NT; ++t) {
            meta[8 + t]  = acc;
            meta[16 + t] = acc;
            acc += ((meta[t] + BM - 1) / BM) * BM;
        }
        meta[8 + NT] = acc;
    }
}

__global__ void scatter_perm_kernel(const int* __restrict__ etype, int E,
                                    int* __restrict__ meta, int* __restrict__ perm) {
    int i = blockIdx.x * blockDim.x + threadIdx.x;
    if (i < E) {
        int pos = atomicAdd(&meta[16 + etype[i]], 1);
        perm[pos] = i;
    }
}

// ---------------- fp32 -> bf16 elementwise (x4) ----------------
__global__ void conv_bf16_kernel(const float* __restrict__ in, unsigned short* __restrict__ out, int n4) {
    int i = blockIdx.x * blockDim.x + threadIdx.x;
    if (i < n4) {
        float4 v = ((const float4*)in)[i];
        ushort4 o;
        o.x = f2bf(v.x); o.y = f2bf(v.y); o.z = f2bf(v.z); o.w = f2bf(v.w);
        ((ushort4*)out)[i] = o;
    }
}

// ---------------- GRU weights -> bf16, transposed B^T[n][k] ----------------
// Brt/Bzt: [512][1024] (k<512 from Wi*, k>=512 from Wh*); Bnit/Bnht: [512][512]
__global__ void conv_gru_w_kernel(const float* __restrict__ Wir, const float* __restrict__ Wiz,
                                  const float* __restrict__ Win, const float* __restrict__ Whr,
                                  const float* __restrict__ Whz, const float* __restrict__ Whn,
                                  unsigned short* __restrict__ Brt, unsigned short* __restrict__ Bzt,
                                  unsigned short* __restrict__ Bnit, unsigned short* __restrict__ Bnht) {
    int idx = blockIdx.x * blockDim.x + threadIdx.x;
    if (idx >= 512 * 1024) return;
    int n = idx >> 10;
    int k = idx & 1023;
    int kk = k & 511;
    const float* wr = (k < 512) ? Wir : Whr;
    const float* wz = (k < 512) ? Wiz : Whz;
    Brt[idx] = f2bf(wr[kk * H + n]);
    Bzt[idx] = f2bf(wz[kk * H + n]);
    if (k < 512) Bnit[n * H + k]  = f2bf(Win[k * H + n]);
    else         Bnht[n * H + kk] = f2bf(Whn[kk * H + n]);
}

// W_edge (512 x 3072) -> WeT[3072][512] bf16
__global__ void conv_edge_w_kernel(const float* __restrict__ W_edge, unsigned short* __restrict__ WeT) {
    int idx = blockIdx.x * blockDim.x + threadIdx.x;
    if (idx >= 3072 * 512) return;
    int n = idx >> 9;
    int k = idx & 511;
    WeT[idx] = f2bf(W_edge[(size_t)k * (NT * H) + n]);
}

// ---------------- edge message GEMM (MFMA) + scatter-add ----------------
__global__ __launch_bounds__(256)
void edge_msg_mfma(const unsigned short* __restrict__ emb_bf,
                   const int* __restrict__ src_idx,
                   const int* __restrict__ dst_idx,
                   const float* __restrict__ b_edge,
                   const unsigned short* __restrict__ WeT,
                   const int* __restrict__ meta,
                   const int* __restrict__ perm,
                   float* __restrict__ proposed)
{
    __shared__ short As[BM][LDW];
    __shared__ short Bs[BN][LDW];
    __shared__ int ls_src[BM];
    __shared__ int ls_dst[BM];

    const int rowBase = blockIdx.y * BM;
    if (rowBase >= meta[8 + NT]) return;
    int t = 0;
    while (rowBase >= meta[8 + t + 1]) ++t;

    const int colBase = blockIdx.x * BN;
    const int tid = threadIdx.x;

    if (tid < BM) {
        int e = perm[rowBase + tid];
        int s = -1, d = -1;
        if (e >= 0) { s = src_idx[e] * H; d = dst_idx[e] * H; }
        ls_src[tid] = s;
        ls_dst[tid] = d;
    }
    __syncthreads();

    const int sRow = tid >> 2;
    const int sK   = (tid & 3) * 8;
    const int lane = tid & 63;
    const int wave = tid >> 6;
    const int wm = (wave >> 1) * 32;
    const int wn = (wave & 1) * 32;
    const int q = lane >> 4;
    const int r = lane & 15;

    f32x4 acc[2][2];
    #pragma unroll
    for (int i = 0; i < 2; ++i)
        #pragma unroll
        for (int j = 0; j < 2; ++j) acc[i][j] = (f32x4){0.f, 0.f, 0.f, 0.f};

    const int sA = ls_src[sRow];
    const size_t bRowBase = ((size_t)(t * H + colBase + sRow)) * H;

    for (int k0 = 0; k0 < H; k0 += BK) {
        uint4 av = make_uint4(0, 0, 0, 0);
        if (sA >= 0) av = *(const uint4*)&emb_bf[(size_t)sA + k0 + sK];
        *(uint4*)&As[sRow][sK] = av;
        *(uint4*)&Bs[sRow][sK] = *(const uint4*)&WeT[bRowBase + k0 + sK];
        __syncthreads();
        #pragma unroll
        for (int i = 0; i < 2; ++i) {
            bf16x8 a = *(const bf16x8*)&As[wm + i * 16 + r][q * 8];
            #pragma unroll
            for (int j = 0; j < 2; ++j) {
                bf16x8 b = *(const bf16x8*)&Bs[wn + j * 16 + r][q * 8];
                acc[i][j] = __builtin_amdgcn_mfma_f32_16x16x32_bf16(a, b, acc[i][j], 0, 0, 0);
            }
        }
        __syncthreads();
    }

    #pragma unroll
    for (int i = 0; i < 2; ++i) {
        #pragma unroll
        for (int reg = 0; reg < 4; ++reg) {
            int rowL = wm + i * 16 + q * 4 + reg;
            int d = ls_dst[rowL];
            if (d < 0) continue;
            #pragma unroll
            for (int j = 0; j < 2; ++j) {
                int col = colBase + wn + j * 16 + r;
                atomicAdd(&proposed[(size_t)d + col], acc[i][j][reg] + b_edge[t * H + col]);
            }
        }
    }
}

// ---------------- fused GRU (MFMA): A' = [P | H] over K=1024 ----------------
__global__ __launch_bounds__(256)
void gru_mfma(const unsigned short* __restrict__ prop_bf,
              const unsigned short* __restrict__ emb_bf,
              const float* __restrict__ emb_f32,
              const unsigned short* __restrict__ Brt,
              const unsigned short* __restrict__ Bzt,
              const unsigned short* __restrict__ Bnit,
              const unsigned short* __restrict__ Bnht,
              const float* __restrict__ bir, const float* __restrict__ biz,
              const float* __restrict__ bin, const float* __restrict__ bhn,
              float* __restrict__ out, int N)
{
    __shared__ short As[BM][LDW];
    __shared__ short Brs[BN][LDW];
    __shared__ short Bzs[BN][LDW];
    __shared__ short Bns[BN][LDW];

    const int rowBase = blockIdx.y * BM;
    const int colBase = blockIdx.x * BN;
    const int tid = threadIdx.x;
    const int sRow = tid >> 2;
    const int sK   = (tid & 3) * 8;
    const int lane = tid & 63;
    const int wave = tid >> 6;
    const int wm = (wave >> 1) * 32;
    const int wn = (wave & 1) * 32;
    const int q = lane >> 4;
    const int r = lane & 15;

    const int aRow = rowBase + sRow;
    const bool aValid = aRow < N;

    f32x4 accR[2][2], accZ[2][2], accNI[2][2], accNH[2][2];
    #pragma unroll
    for (int i = 0; i < 2; ++i)
        #pragma unroll
        for (int j = 0; j < 2; ++j) {
            accR[i][j] = (f32x4){0.f, 0.f, 0.f, 0.f};
            accZ[i][j] = accR[i][j];
            accNI[i][j] = accR[i][j];
            accNH[i][j] = accR[i][j];
        }

    const size_t bRow = (size_t)(colBase + sRow);

    for (int k0 = 0; k0 < 2 * H; k0 += BK) {
        const bool half = (k0 >= H);
        const int kk = half ? (k0 - H) : k0;
        const unsigned short* Asrc = half ? emb_bf : prop_bf;
        uint4 av = make_uint4(0, 0, 0, 0);
        if (aValid) av = *(const uint4*)&Asrc[(size_t)aRow * H + kk + sK];
        *(uint4*)&As[sRow][sK] = av;
        *(uint4*)&Brs[sRow][sK] = *(const uint4*)&Brt[bRow * 1024 + k0 + sK];
        *(uint4*)&Bzs[sRow][sK] = *(const uint4*)&Bzt[bRow * 1024 + k0 + sK];
        const unsigned short* Bn = half ? Bnht : Bnit;
        *(uint4*)&Bns[sRow][sK] = *(const uint4*)&Bn[bRow * H + kk + sK];
        __syncthreads();

        #pragma unroll
        for (int i = 0; i < 2; ++i) {
            bf16x8 a = *(const bf16x8*)&As[wm + i * 16 + r][q * 8];
            #pragma unroll
            for (int j = 0; j < 2; ++j) {
                bf16x8 br = *(const bf16x8*)&Brs[wn + j * 16 + r][q * 8];
                bf16x8 bz = *(const bf16x8*)&Bzs[wn + j * 16 + r][q * 8];
                bf16x8 bn = *(const bf16x8*)&Bns[wn + j * 16 + r][q * 8];
                accR[i][j] = __builtin_amdgcn_mfma_f32_16x16x32_bf16(a, br, accR[i][j], 0, 0, 0);
                accZ[i][j] = __builtin_amdgcn_mfma_f32_16x16x32_bf16(a, bz, accZ[i][j], 0, 0, 0);
                if (half) accNH[i][j] = __builtin_amdgcn_mfma_f32_16x16x32_bf16(a, bn, accNH[i][j], 0, 0, 0);
                else      accNI[i][j] = __builtin_amdgcn_mfma_f32_16x16x32_bf16(a, bn, accNI[i][j], 0, 0, 0);
            }
        }
        __syncthreads();
    }

    #pragma unroll
    for (int i = 0; i < 2; ++i) {
        #pragma unroll
        for (int reg = 0; reg < 4; ++reg) {
            int row = rowBase + wm + i * 16 + q * 4 + reg;
            if (row >= N) continue;
            #pragma unroll
            for (int j = 0; j < 2; ++j) {
                int col = colBase + wn + j * 16 + r;
                float rg = sigmoidf_(accR[i][j][reg] + bir[col]);
                float zg = sigmoidf_(accZ[i][j][reg] + biz[col]);
                float ng = tanhf(accNI[i][j][reg] + bin[col] + rg * (accNH[i][j][reg] + bhn[col]));
                float h = emb_f32[(size_t)row * H + col];
                out[(size_t)row * H + col] = (1.0f - zg) * ng + zg * h;
            }
        }
    }
}

extern "C" void kernel_launch(void* const* d_in, const int* in_sizes, int n_in,
                              void* d_out, int out_size, void* d_ws, size_t ws_size,
                              hipStream_t stream) {
    const float* emb     = (const float*)d_in[0];
    const int*   src_idx = (const int*)d_in[1];
    const int*   dst_idx = (const int*)d_in[2];
    const int*   etype   = (const int*)d_in[3];
    const float* W_edge  = (const float*)d_in[6];
    const float* b_edge  = (const float*)d_in[7];
    const float* Wir = (const float*)d_in[8];
    const float* Wiz = (const float*)d_in[9];
    const float* Win = (const float*)d_in[10];
    const float* bir = (const float*)d_in[11];
    const float* biz = (const float*)d_in[12];
    const float* bin = (const float*)d_in[13];
    const float* Whr = (const float*)d_in[14];
    const float* Whz = (const float*)d_in[15];
    const float* Whn = (const float*)d_in[16];
    const float* bhn = (const float*)d_in[17];

    const int E = in_sizes[1];
    const int N = in_sizes[0] / H;
    const int NH = N * H;

    char* ws = (char*)d_ws;
    float*          proposed = (float*)ws;                       ws += (size_t)NH * 4;
    unsigned short* prop_bf  = (unsigned short*)ws;              ws += (size_t)NH * 2;
    unsigned short* emb_bf   = (unsigned short*)ws;              ws += (size_t)NH * 2;
    unsigned short* Brt      = (unsigned short*)ws;              ws += 512 * 1024 * 2;
    unsigned short* Bzt      = (unsigned short*)ws;              ws += 512 * 1024 * 2;
    unsigned short* Bnit     = (unsigned short*)ws;              ws += 512 * 512 * 2;
    unsigned short* Bnht     = (unsigned short*)ws;              ws += 512 * 512 * 2;
    unsigned short* WeT      = (unsigned short*)ws;              ws += 3072 * 512 * 2;
    int*            meta     = (int*)ws;                         ws += 32 * 4;
    int*            perm     = (int*)ws;
    const int maxRowTiles = (E + BM - 1) / BM + NT;

    hipMemsetAsync(proposed, 0, (size_t)NH * 4, stream);
    hipMemsetAsync(meta, 0, 32 * 4, stream);
    hipMemsetAsync(perm, 0xFF, (size_t)maxRowTiles * BM * 4, stream);

    const int n4 = NH / 4;
    conv_bf16_kernel<<<(n4 + 255) / 256, 256, 0, stream>>>(emb, emb_bf, n4);
    conv_gru_w_kernel<<<(512 * 1024 + 255) / 256, 256, 0, stream>>>(
        Wir, Wiz, Win, Whr, Whz, Whn, Brt, Bzt, Bnit, Bnht);
    conv_edge_w_kernel<<<(3072 * 512 + 255) / 256, 256, 0, stream>>>(W_edge, WeT);

    hist_kernel<<<(E + 255) / 256, 256, 0, stream>>>(etype, E, meta);
    prefix_kernel<<<1, 64, 0, stream>>>(meta);
    scatter_perm_kernel<<<(E + 255) / 256, 256, 0, stream>>>(etype, E, meta, perm);

    dim3 egrid(H / BN, maxRowTiles);
    edge_msg_mfma<<<egrid, 256, 0, stream>>>(emb_bf, src_idx, dst_idx, b_edge, WeT,
                                             meta, perm, proposed);

    conv_bf16_kernel<<<(n4 + 255) / 256, 256, 0, stream>>>(proposed, prop_bf, n4);

    dim3 ggrid(H / BN, (N + BM - 1) / BM);
    gru_mfma<<<ggrid, 256, 0, stream>>>(prop_bf, emb_bf, emb, Brt, Bzt, Bnit, Bnht,
                                        bir, biz, bin, bhn, (float*)d_out, N);
}

// Round 3
// 912.326 us; speedup vs baseline: 4.6343x; 1.9536x over previous
//
#include <hip/hip_runtime.h>
#include <hip/hip_bf16.h>
#include <math.h>

#define H 512
#define NT 6
#define BM 64
#define BN 64
#define BK 32
#define LDW (BK + 8)   // LDS row pitch in shorts (pad 16B)

typedef short bf16x8 __attribute__((ext_vector_type(8)));
typedef float f32x4 __attribute__((ext_vector_type(4)));

__device__ __forceinline__ float sigmoidf_(float x) { return 1.0f / (1.0f + expf(-x)); }

__device__ __forceinline__ unsigned short f2bf(float f) {
    unsigned int u = __float_as_uint(f);
    u = (u + 0x7FFF + ((u >> 16) & 1)) >> 16;
    return (unsigned short)u;
}

// ---------------- edge-type counting sort (block-aggregated atomics) ----------------
// meta layout (ints): [0..7]=counts, [8..14]=paddedStart (NT+1 used), [16..23]=cursor
__global__ void hist_kernel(const int* __restrict__ etype, int E, int* __restrict__ meta) {
    __shared__ int lh[NT];
    if (threadIdx.x < NT) lh[threadIdx.x] = 0;
    __syncthreads();
    int i = blockIdx.x * blockDim.x + threadIdx.x;
    if (i < E) atomicAdd(&lh[etype[i]], 1);
    __syncthreads();
    if (threadIdx.x < NT) {
        int c = lh[threadIdx.x];
        if (c) atomicAdd(&meta[threadIdx.x], c);
    }
}

__global__ void prefix_kernel(int* __restrict__ meta) {
    if (threadIdx.x == 0 && blockIdx.x == 0) {
        int acc = 0;
        for (int t = 0; t < NT; ++t) {
            meta[8 + t]  = acc;
            meta[16 + t] = acc;
            acc += ((meta[t] + BM - 1) / BM) * BM;
        }
        meta[8 + NT] = acc;
    }
}

__global__ void scatter_perm_kernel(const int* __restrict__ etype, int E,
                                    int* __restrict__ meta, int* __restrict__ perm) {
    __shared__ int lcount[NT];
    __shared__ int lbase[NT];
    const int tid = threadIdx.x;
    if (tid < NT) lcount[tid] = 0;
    __syncthreads();
    int i = blockIdx.x * blockDim.x + tid;
    int t = 0, rank = 0;
    if (i < E) {
        t = etype[i];
        rank = atomicAdd(&lcount[t], 1);      // intra-block rank (LDS)
    }
    __syncthreads();
    if (tid < NT) {
        int c = lcount[tid];
        lbase[tid] = c ? atomicAdd(&meta[16 + tid], c) : 0;  // reserve block span
    }
    __syncthreads();
    if (i < E) perm[lbase[t] + rank] = i;
}

// ---------------- fp32 -> bf16 elementwise (x4) ----------------
__global__ void conv_bf16_kernel(const float* __restrict__ in, unsigned short* __restrict__ out, int n4) {
    int i = blockIdx.x * blockDim.x + threadIdx.x;
    if (i < n4) {
        float4 v = ((const float4*)in)[i];
        ushort4 o;
        o.x = f2bf(v.x); o.y = f2bf(v.y); o.z = f2bf(v.z); o.w = f2bf(v.w);
        ((ushort4*)out)[i] = o;
    }
}

// ---------------- GRU weights -> bf16, transposed B^T[n][k] ----------------
__global__ void conv_gru_w_kernel(const float* __restrict__ Wir, const float* __restrict__ Wiz,
                                  const float* __restrict__ Win, const float* __restrict__ Whr,
                                  const float* __restrict__ Whz, const float* __restrict__ Whn,
                                  unsigned short* __restrict__ Brt, unsigned short* __restrict__ Bzt,
                                  unsigned short* __restrict__ Bnit, unsigned short* __restrict__ Bnht) {
    int idx = blockIdx.x * blockDim.x + threadIdx.x;
    if (idx >= 512 * 1024) return;
    int n = idx >> 10;
    int k = idx & 1023;
    int kk = k & 511;
    const float* wr = (k < 512) ? Wir : Whr;
    const float* wz = (k < 512) ? Wiz : Whz;
    Brt[idx] = f2bf(wr[kk * H + n]);
    Bzt[idx] = f2bf(wz[kk * H + n]);
    if (k < 512) Bnit[n * H + k]  = f2bf(Win[k * H + n]);
    else         Bnht[n * H + kk] = f2bf(Whn[kk * H + n]);
}

// W_edge (512 x 3072) -> WeT[3072][512] bf16
__global__ void conv_edge_w_kernel(const float* __restrict__ W_edge, unsigned short* __restrict__ WeT) {
    int idx = blockIdx.x * blockDim.x + threadIdx.x;
    if (idx >= 3072 * 512) return;
    int n = idx >> 9;
    int k = idx & 511;
    WeT[idx] = f2bf(W_edge[(size_t)k * (NT * H) + n]);
}

// ---------------- edge message GEMM (MFMA) + scatter-add ----------------
__global__ __launch_bounds__(256)
void edge_msg_mfma(const unsigned short* __restrict__ emb_bf,
                   const int* __restrict__ src_idx,
                   const int* __restrict__ dst_idx,
                   const float* __restrict__ b_edge,
                   const unsigned short* __restrict__ WeT,
                   const int* __restrict__ meta,
                   const int* __restrict__ perm,
                   float* __restrict__ proposed)
{
    __shared__ short As[BM][LDW];
    __shared__ short Bs[BN][LDW];
    __shared__ int ls_src[BM];
    __shared__ int ls_dst[BM];

    const int rowBase = blockIdx.y * BM;
    if (rowBase >= meta[8 + NT]) return;
    int t = 0;
    while (rowBase >= meta[8 + t + 1]) ++t;

    const int colBase = blockIdx.x * BN;
    const int tid = threadIdx.x;

    if (tid < BM) {
        int e = perm[rowBase + tid];
        int s = -1, d = -1;
        if (e >= 0) { s = src_idx[e] * H; d = dst_idx[e] * H; }
        ls_src[tid] = s;
        ls_dst[tid] = d;
    }
    __syncthreads();

    const int sRow = tid >> 2;
    const int sK   = (tid & 3) * 8;
    const int lane = tid & 63;
    const int wave = tid >> 6;
    const int wm = (wave >> 1) * 32;
    const int wn = (wave & 1) * 32;
    const int q = lane >> 4;
    const int r = lane & 15;

    f32x4 acc[2][2];
    #pragma unroll
    for (int i = 0; i < 2; ++i)
        #pragma unroll
        for (int j = 0; j < 2; ++j) acc[i][j] = (f32x4){0.f, 0.f, 0.f, 0.f};

    const int sA = ls_src[sRow];
    const size_t bRowBase = ((size_t)(t * H + colBase + sRow)) * H;

    for (int k0 = 0; k0 < H; k0 += BK) {
        uint4 av = make_uint4(0, 0, 0, 0);
        if (sA >= 0) av = *(const uint4*)&emb_bf[(size_t)sA + k0 + sK];
        *(uint4*)&As[sRow][sK] = av;
        *(uint4*)&Bs[sRow][sK] = *(const uint4*)&WeT[bRowBase + k0 + sK];
        __syncthreads();
        #pragma unroll
        for (int i = 0; i < 2; ++i) {
            bf16x8 a = *(const bf16x8*)&As[wm + i * 16 + r][q * 8];
            #pragma unroll
            for (int j = 0; j < 2; ++j) {
                bf16x8 b = *(const bf16x8*)&Bs[wn + j * 16 + r][q * 8];
                acc[i][j] = __builtin_amdgcn_mfma_f32_16x16x32_bf16(a, b, acc[i][j], 0, 0, 0);
            }
        }
        __syncthreads();
    }

    #pragma unroll
    for (int i = 0; i < 2; ++i) {
        #pragma unroll
        for (int reg = 0; reg < 4; ++reg) {
            int rowL = wm + i * 16 + q * 4 + reg;
            int d = ls_dst[rowL];
            if (d < 0) continue;
            #pragma unroll
            for (int j = 0; j < 2; ++j) {
                int col = colBase + wn + j * 16 + r;
                atomicAdd(&proposed[(size_t)d + col], acc[i][j][reg] + b_edge[t * H + col]);
            }
        }
    }
}

// ---------------- fused GRU (MFMA): A' = [P | H] over K=1024 ----------------
__global__ __launch_bounds__(256)
void gru_mfma(const unsigned short* __restrict__ prop_bf,
              const unsigned short* __restrict__ emb_bf,
              const float* __restrict__ emb_f32,
              const unsigned short* __restrict__ Brt,
              const unsigned short* __restrict__ Bzt,
              const unsigned short* __restrict__ Bnit,
              const unsigned short* __restrict__ Bnht,
              const float* __restrict__ bir, const float* __restrict__ biz,
              const float* __restrict__ bin, const float* __restrict__ bhn,
              float* __restrict__ out, int N)
{
    __shared__ short As[BM][LDW];
    __shared__ short Brs[BN][LDW];
    __shared__ short Bzs[BN][LDW];
    __shared__ short Bns[BN][LDW];

    const int rowBase = blockIdx.y * BM;
    const int colBase = blockIdx.x * BN;
    const int tid = threadIdx.x;
    const int sRow = tid >> 2;
    const int sK   = (tid & 3) * 8;
    const int lane = tid & 63;
    const int wave = tid >> 6;
    const int wm = (wave >> 1) * 32;
    const int wn = (wave & 1) * 32;
    const int q = lane >> 4;
    const int r = lane & 15;

    const int aRow = rowBase + sRow;
    const bool aValid = aRow < N;

    f32x4 accR[2][2], accZ[2][2], accNI[2][2], accNH[2][2];
    #pragma unroll
    for (int i = 0; i < 2; ++i)
        #pragma unroll
        for (int j = 0; j < 2; ++j) {
            accR[i][j] = (f32x4){0.f, 0.f, 0.f, 0.f};
            accZ[i][j] = accR[i][j];
            accNI[i][j] = accR[i][j];
            accNH[i][j] = accR[i][j];
        }

    const size_t bRow = (size_t)(colBase + sRow);

    for (int k0 = 0; k0 < 2 * H; k0 += BK) {
        const bool half = (k0 >= H);
        const int kk = half ? (k0 - H) : k0;
        const unsigned short* Asrc = half ? emb_bf : prop_bf;
        uint4 av = make_uint4(0, 0, 0, 0);
        if (aValid) av = *(const uint4*)&Asrc[(size_t)aRow * H + kk + sK];
        *(uint4*)&As[sRow][sK] = av;
        *(uint4*)&Brs[sRow][sK] = *(const uint4*)&Brt[bRow * 1024 + k0 + sK];
        *(uint4*)&Bzs[sRow][sK] = *(const uint4*)&Bzt[bRow * 1024 + k0 + sK];
        const unsigned short* Bn = half ? Bnht : Bnit;
        *(uint4*)&Bns[sRow][sK] = *(const uint4*)&Bn[bRow * H + kk + sK];
        __syncthreads();

        #pragma unroll
        for (int i = 0; i < 2; ++i) {
            bf16x8 a = *(const bf16x8*)&As[wm + i * 16 + r][q * 8];
            #pragma unroll
            for (int j = 0; j < 2; ++j) {
                bf16x8 br = *(const bf16x8*)&Brs[wn + j * 16 + r][q * 8];
                bf16x8 bz = *(const bf16x8*)&Bzs[wn + j * 16 + r][q * 8];
                bf16x8 bn = *(const bf16x8*)&Bns[wn + j * 16 + r][q * 8];
                accR[i][j] = __builtin_amdgcn_mfma_f32_16x16x32_bf16(a, br, accR[i][j], 0, 0, 0);
                accZ[i][j] = __builtin_amdgcn_mfma_f32_16x16x32_bf16(a, bz, accZ[i][j], 0, 0, 0);
                if (half) accNH[i][j] = __builtin_amdgcn_mfma_f32_16x16x32_bf16(a, bn, accNH[i][j], 0, 0, 0);
                else      accNI[i][j] = __builtin_amdgcn_mfma_f32_16x16x32_bf16(a, bn, accNI[i][j], 0, 0, 0);
            }
        }
        __syncthreads();
    }

    #pragma unroll
    for (int i = 0; i < 2; ++i) {
        #pragma unroll
        for (int reg = 0; reg < 4; ++reg) {
            int row = rowBase + wm + i * 16 + q * 4 + reg;
            if (row >= N) continue;
            #pragma unroll
            for (int j = 0; j < 2; ++j) {
                int col = colBase + wn + j * 16 + r;
                float rg = sigmoidf_(accR[i][j][reg] + bir[col]);
                float zg = sigmoidf_(accZ[i][j][reg] + biz[col]);
                float ng = tanhf(accNI[i][j][reg] + bin[col] + rg * (accNH[i][j][reg] + bhn[col]));
                float h = emb_f32[(size_t)row * H + col];
                out[(size_t)row * H + col] = (1.0f - zg) * ng + zg * h;
            }
        }
    }
}

extern "C" void kernel_launch(void* const* d_in, const int* in_sizes, int n_in,
                              void* d_out, int out_size, void* d_ws, size_t ws_size,
                              hipStream_t stream) {
    const float* emb     = (const float*)d_in[0];
    const int*   src_idx = (const int*)d_in[1];
    const int*   dst_idx = (const int*)d_in[2];
    const int*   etype   = (const int*)d_in[3];
    const float* W_edge  = (const float*)d_in[6];
    const float* b_edge  = (const float*)d_in[7];
    const float* Wir = (const float*)d_in[8];
    const float* Wiz = (const float*)d_in[9];
    const float* Win = (const float*)d_in[10];
    const float* bir = (const float*)d_in[11];
    const float* biz = (const float*)d_in[12];
    const float* bin = (const float*)d_in[13];
    const float* Whr = (const float*)d_in[14];
    const float* Whz = (const float*)d_in[15];
    const float* Whn = (const float*)d_in[16];
    const float* bhn = (const float*)d_in[17];

    const int E = in_sizes[1];
    const int N = in_sizes[0] / H;
    const int NH = N * H;

    char* ws = (char*)d_ws;
    float*          proposed = (float*)ws;                       ws += (size_t)NH * 4;
    unsigned short* prop_bf  = (unsigned short*)ws;              ws += (size_t)NH * 2;
    unsigned short* emb_bf   = (unsigned short*)ws;              ws += (size_t)NH * 2;
    unsigned short* Brt      = (unsigned short*)ws;              ws += 512 * 1024 * 2;
    unsigned short* Bzt      = (unsigned short*)ws;              ws += 512 * 1024 * 2;
    unsigned short* Bnit     = (unsigned short*)ws;              ws += 512 * 512 * 2;
    unsigned short* Bnht     = (unsigned short*)ws;              ws += 512 * 512 * 2;
    unsigned short* WeT      = (unsigned short*)ws;              ws += 3072 * 512 * 2;
    int*            meta     = (int*)ws;                         ws += 32 * 4;
    int*            perm     = (int*)ws;
    const int maxRowTiles = (E + BM - 1) / BM + NT;

    hipMemsetAsync(proposed, 0, (size_t)NH * 4, stream);
    hipMemsetAsync(meta, 0, 32 * 4, stream);
    hipMemsetAsync(perm, 0xFF, (size_t)maxRowTiles * BM * 4, stream);

    const int n4 = NH / 4;
    conv_bf16_kernel<<<(n4 + 255) / 256, 256, 0, stream>>>(emb, emb_bf, n4);
    conv_gru_w_kernel<<<(512 * 1024 + 255) / 256, 256, 0, stream>>>(
        Wir, Wiz, Win, Whr, Whz, Whn, Brt, Bzt, Bnit, Bnht);
    conv_edge_w_kernel<<<(3072 * 512 + 255) / 256, 256, 0, stream>>>(W_edge, WeT);

    hist_kernel<<<(E + 255) / 256, 256, 0, stream>>>(etype, E, meta);
    prefix_kernel<<<1, 64, 0, stream>>>(meta);
    scatter_perm_kernel<<<(E + 255) / 256, 256, 0, stream>>>(etype, E, meta, perm);

    dim3 egrid(H / BN, maxRowTiles);
    edge_msg_mfma<<<egrid, 256, 0, stream>>>(emb_bf, src_idx, dst_idx, b_edge, WeT,
                                             meta, perm, proposed);

    conv_bf16_kernel<<<(n4 + 255) / 256, 256, 0, stream>>>(proposed, prop_bf, n4);

    dim3 ggrid(H / BN, (N + BM - 1) / BM);
    gru_mfma<<<ggrid, 256, 0, stream>>>(prop_bf, emb_bf, emb, Brt, Bzt, Bnit, Bnht,
                                        bir, biz, bin, bhn, (float*)d_out, N);
}